// Round 7
// baseline (617.628 us; speedup 1.0000x reference)
//
#include <hip/hip_runtime.h>
#include <hip/hip_bf16.h>
#include <cstdint>
#include <cstddef>

// Problem: B=1, T=4096, C=1024, NH=16, HD=64. fp32 I/O, bf16 internal compute.
// Pipeline: convert x -> bf16; transpose+convert Wqkv -> B^T bf16; rope table;
//           GEMM1(+bias+RoPE, vectorized LDS-transposed epilogue stores)
//           -> transpose Wproj (overwrites rope table region)
//           -> flash attention (S-transposed, 1 q-tile/block, 4 indep waves)
//           -> GEMM2(+bias) -> fp32 out.
// Workspace footprint: 40 MiB total (Y aliases xb; rope table aliases WprojT).
constexpr int TSEQ = 4096;
constexpr int CDIM = 1024;
constexpr int NHEAD = 16;
constexpr int HDIM = 64;

using bf16 = __hip_bfloat16;
typedef __bf16 bf16x8 __attribute__((ext_vector_type(8)));
typedef float floatx4 __attribute__((ext_vector_type(4)));

// -------- elementwise fp32 -> bf16 (4 elems/thread) --------
__global__ __launch_bounds__(256) void f32_to_bf16(
    const float4* __restrict__ in, uint64_t* __restrict__ out, int n4) {
  const int i = blockIdx.x * 256 + threadIdx.x;
  if (i < n4) {
    const float4 v = in[i];
    union { bf16 h[4]; uint64_t u; } p;
    p.h[0] = __float2bfloat16(v.x);
    p.h[1] = __float2bfloat16(v.y);
    p.h[2] = __float2bfloat16(v.z);
    p.h[3] = __float2bfloat16(v.w);
    out[i] = p.u;
  }
}

// -------- rope table: tab[t][0..31]=cos(t*invf_j), tab[t][32..63]=sin --------
__global__ __launch_bounds__(256) void rope_table(float* __restrict__ tab) {
  const int i = blockIdx.x * 256 + threadIdx.x;  // over TSEQ*32
  const int t = i >> 5, j = i & 31;
  const float invf = exp2f((float)j * (-2.0f / 64.0f) * 13.287712379549449f);
  float sn, cs;
  sincosf((float)t * invf, &sn, &cs);
  tab[t * 64 + j] = cs;
  tab[t * 64 + 32 + j] = sn;
}

// -------- transpose + convert (fp32 -> bf16), out[c][r] = in[r][c] --------
__global__ __launch_bounds__(256) void transpose_f32_bf16(
    const float* __restrict__ in, bf16* __restrict__ out, int R, int C) {
  __shared__ float tile[32][33];
  const int c0 = blockIdx.x * 32, r0 = blockIdx.y * 32;
  const int tx = threadIdx.x, ty = threadIdx.y;  // 32 x 8
#pragma unroll
  for (int i = 0; i < 32; i += 8)
    tile[ty + i][tx] = in[(size_t)(r0 + ty + i) * C + c0 + tx];
  __syncthreads();
#pragma unroll
  for (int i = 0; i < 32; i += 8)
    out[(size_t)(c0 + ty + i) * R + r0 + tx] = __float2bfloat16(tile[tx][ty + i]);
}

// -------- GEMM: C = A(MxK,bf16) * Bt(NxK,bf16)^T + bias(fp32) --------
// MODE 0: fp32 output to Cout[M][N] (vectorized via LDS transpose scratch).
// MODE 1: qkv epilogue: cols [0,1024)=q, [1024,2048)=k -> RoPE (table) ->
//         Qh/Kh[h][t][64]; cols [2048,3072)=v -> Vt[h][d][t]. All stores are
//         LDS-staged then 16B/lane contiguous (1KB per instruction).
template <int MODE>
__global__ __launch_bounds__(256) void gemm_bt(
    const bf16* __restrict__ A, const bf16* __restrict__ Bt,
    const float* __restrict__ bias, const float* __restrict__ tab,
    float* __restrict__ Cout,
    bf16* __restrict__ Qh, bf16* __restrict__ Kh, bf16* __restrict__ Vt,
    int M, int N, int K) {
  // 36.9KB shared: sized for the epilogue scratch (4 waves x 64x72 bf16 =
  // 36864B); the K-loop staging (2 x 128 x 40 bf16 = 20480B) uses the front.
  __shared__ __align__(16) bf16 smem[4 * 64 * 72];
  bf16* As = smem;              // As[r][c] = smem[r*40+c]
  bf16* Bs = smem + 128 * 40;
  const int tid = threadIdx.x;
  const int m0 = blockIdx.y * 128, n0 = blockIdx.x * 128;
  const int wave = tid >> 6, lane = tid & 63;
  const int l15 = lane & 15, quad = lane >> 4;
  const int wm = (wave >> 1) * 64, wn = (wave & 1) * 64;

  const floatx4 fzero = {0.f, 0.f, 0.f, 0.f};
  floatx4 acc[4][4];
#pragma unroll
  for (int mi = 0; mi < 4; mi++)
#pragma unroll
    for (int ni = 0; ni < 4; ni++) acc[mi][ni] = fzero;

  const int row0 = tid >> 2;            // 0..63
  const int colb = (tid & 3) << 3;      // 0,8,16,24

  for (int k0 = 0; k0 < K; k0 += 32) {
    __syncthreads();
    *(float4*)(As + row0 * 40 + colb) =
        *(const float4*)(A + (size_t)(m0 + row0) * K + k0 + colb);
    *(float4*)(As + (row0 + 64) * 40 + colb) =
        *(const float4*)(A + (size_t)(m0 + row0 + 64) * K + k0 + colb);
    *(float4*)(Bs + row0 * 40 + colb) =
        *(const float4*)(Bt + (size_t)(n0 + row0) * K + k0 + colb);
    *(float4*)(Bs + (row0 + 64) * 40 + colb) =
        *(const float4*)(Bt + (size_t)(n0 + row0 + 64) * K + k0 + colb);
    __syncthreads();

    bf16x8 a[4], b[4];
#pragma unroll
    for (int mi = 0; mi < 4; mi++)
      a[mi] = *(const bf16x8*)(As + (wm + mi * 16 + l15) * 40 + quad * 8);
#pragma unroll
    for (int ni = 0; ni < 4; ni++)
      b[ni] = *(const bf16x8*)(Bs + (wn + ni * 16 + l15) * 40 + quad * 8);
#pragma unroll
    for (int mi = 0; mi < 4; mi++)
#pragma unroll
      for (int ni = 0; ni < 4; ni++)
        acc[mi][ni] = __builtin_amdgcn_mfma_f32_16x16x32_bf16(
            a[mi], b[ni], acc[mi][ni], 0, 0, 0);
  }

  // ---- Epilogue. C/D layout: col = lane&15, row = quad*4 + reg. ----
  __syncthreads();  // all waves done with As/Bs; reuse as scratch

  if (MODE == 1) {
    bf16* ep = smem + (size_t)wave * (64 * 72);  // 4 x 9216B = 36864B
    const int cbase = n0 + wn;                   // multiple of 64
    const int sec = cbase >> 10;                 // 0=q 1=k 2=v (wave-uniform)
    const int hh = (cbase & 1023) >> 6;          // head (uniform per wave)
    if (sec == 2) {
      // stage V^T: ep[d][t_rel], stride 72
#pragma unroll
      for (int ni = 0; ni < 4; ni++) {
        const int d = ni * 16 + l15;
        const float bv = bias[cbase + d];
#pragma unroll
        for (int mi = 0; mi < 4; mi++)
#pragma unroll
          for (int r = 0; r < 4; r++)
            ep[(size_t)d * 72 + mi * 16 + quad * 4 + r] =
                __float2bfloat16(acc[mi][ni][r] + bv);
      }
      __asm__ __volatile__("" ::: "memory");  // same-wave DS order
#pragma unroll
      for (int it = 0; it < 8; it++) {
        const int dr = it * 8 + (lane >> 3);
        const int t8 = (lane & 7) * 8;
        const bf16x8 vv = *(const bf16x8*)(ep + (size_t)dr * 72 + t8);
        *(bf16x8*)(Vt + ((size_t)hh * HDIM + dr) * TSEQ + m0 + wm + t8) = vv;
      }
    } else {
      bf16* dst = (sec == 0) ? Qh : Kh;
      // stage RoPE'd rows: ep[t_rel][c], stride 72
#pragma unroll
      for (int ni = 0; ni < 4; ni++) {
        const int c = ni * 16 + l15;  // == d, 0..63
        const float bv = bias[cbase + c];
        const int j = c & 31;
#pragma unroll
        for (int mi = 0; mi < 4; mi++) {
#pragma unroll
          for (int r = 0; r < 4; r++) {
            const int t = m0 + wm + mi * 16 + quad * 4 + r;
            const float v = acc[mi][ni][r] + bv;
            const float partner = __shfl_xor(v, 1, 64);  // col^1 in lane^1
            const float cs = tab[t * 64 + j];
            const float sn = tab[t * 64 + 32 + j];
            const float res = v * cs + ((c & 1) ? partner : -partner) * sn;
            ep[(size_t)(mi * 16 + quad * 4 + r) * 72 + c] =
                __float2bfloat16(res);
          }
        }
      }
      __asm__ __volatile__("" ::: "memory");
#pragma unroll
      for (int it = 0; it < 8; it++) {
        const int row = it * 8 + (lane >> 3);
        const int c8 = (lane & 7) * 8;
        const bf16x8 vv = *(const bf16x8*)(ep + (size_t)row * 72 + c8);
        *(bf16x8*)(dst + ((size_t)hh * TSEQ + m0 + wm + row) * HDIM + c8) = vv;
      }
    }
  } else {
    float* ep32 = (float*)smem + (size_t)wave * (32 * 68);  // 4 x 8704B
    float bvv[4];
#pragma unroll
    for (int ni = 0; ni < 4; ni++) bvv[ni] = bias[n0 + wn + ni * 16 + l15];
#pragma unroll
    for (int half = 0; half < 2; half++) {
      if (half) __asm__ __volatile__("" ::: "memory");
#pragma unroll
      for (int ni = 0; ni < 4; ni++)
#pragma unroll
        for (int mi2 = 0; mi2 < 2; mi2++)
#pragma unroll
          for (int r = 0; r < 4; r++)
            ep32[(size_t)(mi2 * 16 + quad * 4 + r) * 68 + ni * 16 + l15] =
                acc[half * 2 + mi2][ni][r] + bvv[ni];
      __asm__ __volatile__("" ::: "memory");
#pragma unroll
      for (int it = 0; it < 8; it++) {
        const int row = it * 4 + (lane >> 4);
        const float4 vv = *(const float4*)(ep32 + (size_t)row * 68 + l15 * 4);
        *(float4*)(Cout + (size_t)(m0 + wm + half * 32 + row) * N + n0 + wn +
                   l15 * 4) = vv;
      }
    }
  }
}

// -------- flash attention, S-transposed, one 64-row q-tile per block --------
// grid (64, NHEAD), 256 threads = 4 INDEPENDENT waves (no barriers).
// Wave w owns 16 q-rows: q = t*64 + w*16 + l15 (col of S^T). Block's q-tile
// t = 63 - blockIdx.x so heavy tiles launch first; light blocks backfill.
// S^T = K(A-frag) x Q(B-frag): col=lane&15=q, row=quad*4+r=kv -> per-lane
// row-stats (2 shfls), O^T = V^T(A) x P^T(B): col=q, row=d.
__global__ __launch_bounds__(256) void attn_kernel(
    const bf16* __restrict__ Qh, const bf16* __restrict__ Kh,
    const bf16* __restrict__ Vt, bf16* __restrict__ Y) {
  const int h = blockIdx.y;
  const int t = 63 - blockIdx.x;  // q-tile (64 rows), heavy first
  const int tid = threadIdx.x;
  const int w = tid >> 6, lane = tid & 63;
  const int l15 = lane & 15, quad = lane >> 4;
  const int q = t * 64 + w * 16 + l15;  // this wave's q-row
  const int nkv = t + 1;                // 64-wide kv tiles

  const bf16* Qb = Qh + (size_t)h * TSEQ * HDIM;
  const bf16* Kb = Kh + (size_t)h * TSEQ * HDIM;
  const bf16* Vb = Vt + (size_t)h * HDIM * TSEQ;

  // per-wave P^T scratch: [q-row 0..15][kv 0..63], stride 72 bf16
  __shared__ bf16 Plds[4][16][72];

  // Q B-fragment: n=l15 (q-row), k=quad*8+j (+32*ks) over d
  bf16x8 qf[2];
#pragma unroll
  for (int ks = 0; ks < 2; ks++)
    qf[ks] = *(const bf16x8*)(Qb + (size_t)q * HDIM + ks * 32 + quad * 8);

  const floatx4 fzero = {0.f, 0.f, 0.f, 0.f};
  floatx4 o[4];  // O^T: col=q(l15), row=d=dt*16+quad*4+r
  float m_i = -1e30f, l_i = 0.f;
#pragma unroll
  for (int dt = 0; dt < 4; dt++) o[dt] = fzero;

  const float sc = 0.125f * 1.4426950408889634f;  // 1/sqrt(64) * log2(e)

  for (int kb = 0; kb < nkv; kb++) {
    const int kv0 = kb * 64;
    const bool maskit = (kb == nkv - 1);

    // K A-fragments: m=l15 (kv), k=quad*8+j over d
    bf16x8 kf[4][2];
#pragma unroll
    for (int kt = 0; kt < 4; kt++)
#pragma unroll
      for (int ks = 0; ks < 2; ks++)
        kf[kt][ks] = *(const bf16x8*)(Kb +
            (size_t)(kv0 + kt * 16 + l15) * HDIM + ks * 32 + quad * 8);

    floatx4 s[4];
#pragma unroll
    for (int kt = 0; kt < 4; kt++) s[kt] = fzero;
#pragma unroll
    for (int kt = 0; kt < 4; kt++)
#pragma unroll
      for (int ks = 0; ks < 2; ks++)
        s[kt] = __builtin_amdgcn_mfma_f32_16x16x32_bf16(
            kf[kt][ks], qf[ks], s[kt], 0, 0, 0);

    // V A-fragments (independent of softmax; overlap): m=d, k over kv
    bf16x8 vf[4][2];
#pragma unroll
    for (int dt = 0; dt < 4; dt++)
#pragma unroll
      for (int ks = 0; ks < 2; ks++)
        vf[dt][ks] = *(const bf16x8*)(Vb +
            (size_t)(dt * 16 + l15) * TSEQ + kv0 + ks * 32 + quad * 8);

    // online softmax: lane owns its q-row's 16 kv values (2 shfls total)
#pragma unroll
    for (int kt = 0; kt < 4; kt++) {
#pragma unroll
      for (int r = 0; r < 4; r++) {
        const float v = s[kt][r] * sc;
        if (maskit) {
          const int kv = kv0 + kt * 16 + quad * 4 + r;
          s[kt][r] = (kv <= q) ? v : -1e30f;
        } else {
          s[kt][r] = v;
        }
      }
    }
    float mx = -1e30f;
#pragma unroll
    for (int kt = 0; kt < 4; kt++)
#pragma unroll
      for (int r = 0; r < 4; r++) mx = fmaxf(mx, s[kt][r]);
    mx = fmaxf(mx, __shfl_xor(mx, 16, 64));
    mx = fmaxf(mx, __shfl_xor(mx, 32, 64));
    const float mnew = fmaxf(m_i, mx);
    const float alpha = exp2f(m_i - mnew);
    m_i = mnew;
    float rsum = 0.f;
#pragma unroll
    for (int kt = 0; kt < 4; kt++) {
#pragma unroll
      for (int r = 0; r < 4; r++) {
        const float pv = exp2f(s[kt][r] - mnew);
        s[kt][r] = pv;
        rsum += pv;
      }
    }
    rsum += __shfl_xor(rsum, 16, 64);
    rsum += __shfl_xor(rsum, 32, 64);
    l_i = l_i * alpha + rsum;
#pragma unroll
    for (int dt = 0; dt < 4; dt++) o[dt] *= alpha;

    // pack P^T to LDS: row=l15 (q), col=kt*16+quad*4 (+r), 4 bf16 = b64
#pragma unroll
    for (int kt = 0; kt < 4; kt++) {
      union { bf16 hh[4]; uint64_t u; } pk;
#pragma unroll
      for (int r = 0; r < 4; r++) pk.hh[r] = __float2bfloat16(s[kt][r]);
      *(uint64_t*)(&Plds[w][l15][kt * 16 + quad * 4]) = pk.u;
    }
    __asm__ __volatile__("" ::: "memory");  // same-wave DS order

    // P^T B-fragment: n=q(l15), k=kv=ks*32+quad*8..+7
    bf16x8 pf[2];
#pragma unroll
    for (int ks = 0; ks < 2; ks++)
      pf[ks] = *(const bf16x8*)(&Plds[w][l15][ks * 32 + quad * 8]);
#pragma unroll
    for (int dt = 0; dt < 4; dt++)
#pragma unroll
      for (int ks = 0; ks < 2; ks++)
        o[dt] = __builtin_amdgcn_mfma_f32_16x16x32_bf16(
            vf[dt][ks], pf[ks], o[dt], 0, 0, 0);
  }

  // epilogue: O^T col=q(l15), row=d=dt*16+quad*4+r; write Y[q][h*64+d]
  const float inv = 1.0f / l_i;
#pragma unroll
  for (int dt = 0; dt < 4; dt++) {
    union { bf16 hh[4]; uint64_t u; } pk;
#pragma unroll
    for (int r = 0; r < 4; r++)
      pk.hh[r] = __float2bfloat16(o[dt][r] * inv);
    *(uint64_t*)(Y + (size_t)q * CDIM + h * HDIM + dt * 16 + quad * 4) = pk.u;
  }
}

extern "C" void kernel_launch(void* const* d_in, const int* in_sizes, int n_in,
                              void* d_out, int out_size, void* d_ws,
                              size_t ws_size, hipStream_t stream) {
  const float* x     = (const float*)d_in[0];
  const float* Wqkv  = (const float*)d_in[1];
  const float* bqkv  = (const float*)d_in[2];
  const float* Wproj = (const float*)d_in[3];
  const float* bproj = (const float*)d_in[4];
  float* out = (float*)d_out;

  // 40 MiB workspace layout; Y aliases xb (xb dead after gemm1);
  // rope table aliases WprojT (WprojT transposed after gemm1).
  char* ws = (char*)d_ws;
  bf16* xb     = (bf16*)(ws);                        // 4096x1024 = 8 MiB
  bf16* Y      = (bf16*)(ws);                        // aliases xb
  bf16* WqkvT  = (bf16*)(ws + (8ull  << 20));        // 3072x1024 = 6 MiB
  bf16* WprojT = (bf16*)(ws + (14ull << 20));        // 1024x1024 = 2 MiB
  float* tab   = (float*)(ws + (14ull << 20));       // 4096x64 fp32 = 1 MiB
  bf16* Qh     = (bf16*)(ws + (16ull << 20));        // [16][4096][64] = 8 MiB
  bf16* Kh     = (bf16*)(ws + (24ull << 20));        // 8 MiB
  bf16* Vt     = (bf16*)(ws + (32ull << 20));        // [16][64][4096] = 8 MiB

  f32_to_bf16<<<dim3(4096), 256, 0, stream>>>((const float4*)x, (uint64_t*)xb,
                                              TSEQ * CDIM / 4);
  transpose_f32_bf16<<<dim3(96, 32), dim3(32, 8), 0, stream>>>(
      Wqkv, WqkvT, CDIM, 3 * CDIM);
  rope_table<<<dim3(TSEQ * 32 / 256), 256, 0, stream>>>(tab);
  gemm_bt<1><<<dim3(24, 32), 256, 0, stream>>>(
      xb, WqkvT, bqkv, tab, (float*)nullptr, Qh, Kh, Vt, TSEQ, 3 * CDIM, CDIM);
  transpose_f32_bf16<<<dim3(32, 32), dim3(32, 8), 0, stream>>>(
      Wproj, WprojT, CDIM, CDIM);  // overwrites tab (dead after gemm1)
  attn_kernel<<<dim3(64, 16), 256, 0, stream>>>(Qh, Kh, Vt, Y);
  gemm_bt<0><<<dim3(8, 32), 256, 0, stream>>>(
      Y, WprojT, bproj, (float*)nullptr, out, (bf16*)nullptr, (bf16*)nullptr,
      (bf16*)nullptr, TSEQ, CDIM, CDIM);
}

// Round 8
// 400.226 us; speedup vs baseline: 1.5432x; 1.5432x over previous
//
#include <hip/hip_runtime.h>
#include <hip/hip_bf16.h>
#include <cstdint>
#include <cstddef>

// Problem: B=1, T=4096, C=1024, NH=16, HD=64. fp32 I/O, bf16 internal compute.
// Pipeline: convert x -> bf16; transpose+convert Wqkv -> B^T bf16; rope table;
//           GEMM1(+bias+RoPE, vectorized LDS-transposed epilogue stores)
//           -> transpose Wproj (overwrites rope table region)
//           -> flash attention (S-transposed, paired q-tiles = 2 chains/wave,
//              K-fragment register double-buffer prefetch)
//           -> GEMM2(+bias) -> fp32 out.
// Workspace footprint: 40 MiB total (Y aliases xb; rope table aliases WprojT).
constexpr int TSEQ = 4096;
constexpr int CDIM = 1024;
constexpr int NHEAD = 16;
constexpr int HDIM = 64;

using bf16 = __hip_bfloat16;
typedef __bf16 bf16x8 __attribute__((ext_vector_type(8)));
typedef float floatx4 __attribute__((ext_vector_type(4)));

// -------- elementwise fp32 -> bf16 (4 elems/thread) --------
__global__ __launch_bounds__(256) void f32_to_bf16(
    const float4* __restrict__ in, uint64_t* __restrict__ out, int n4) {
  const int i = blockIdx.x * 256 + threadIdx.x;
  if (i < n4) {
    const float4 v = in[i];
    union { bf16 h[4]; uint64_t u; } p;
    p.h[0] = __float2bfloat16(v.x);
    p.h[1] = __float2bfloat16(v.y);
    p.h[2] = __float2bfloat16(v.z);
    p.h[3] = __float2bfloat16(v.w);
    out[i] = p.u;
  }
}

// -------- rope table: tab[t][0..31]=cos(t*invf_j), tab[t][32..63]=sin --------
__global__ __launch_bounds__(256) void rope_table(float* __restrict__ tab) {
  const int i = blockIdx.x * 256 + threadIdx.x;  // over TSEQ*32
  const int t = i >> 5, j = i & 31;
  const float invf = exp2f((float)j * (-2.0f / 64.0f) * 13.287712379549449f);
  float sn, cs;
  sincosf((float)t * invf, &sn, &cs);
  tab[t * 64 + j] = cs;
  tab[t * 64 + 32 + j] = sn;
}

// -------- transpose + convert (fp32 -> bf16), out[c][r] = in[r][c] --------
__global__ __launch_bounds__(256) void transpose_f32_bf16(
    const float* __restrict__ in, bf16* __restrict__ out, int R, int C) {
  __shared__ float tile[32][33];
  const int c0 = blockIdx.x * 32, r0 = blockIdx.y * 32;
  const int tx = threadIdx.x, ty = threadIdx.y;  // 32 x 8
#pragma unroll
  for (int i = 0; i < 32; i += 8)
    tile[ty + i][tx] = in[(size_t)(r0 + ty + i) * C + c0 + tx];
  __syncthreads();
#pragma unroll
  for (int i = 0; i < 32; i += 8)
    out[(size_t)(c0 + ty + i) * R + r0 + tx] = __float2bfloat16(tile[tx][ty + i]);
}

// -------- GEMM: C = A(MxK,bf16) * Bt(NxK,bf16)^T + bias(fp32) --------
// MODE 0: fp32 output to Cout[M][N] (vectorized via LDS transpose scratch).
// MODE 1: qkv epilogue: cols [0,1024)=q, [1024,2048)=k -> RoPE (table) ->
//         Qh/Kh[h][t][64]; cols [2048,3072)=v -> Vt[h][d][t]. All stores are
//         LDS-staged then 16B/lane contiguous (1KB per instruction).
template <int MODE>
__global__ __launch_bounds__(256) void gemm_bt(
    const bf16* __restrict__ A, const bf16* __restrict__ Bt,
    const float* __restrict__ bias, const float* __restrict__ tab,
    float* __restrict__ Cout,
    bf16* __restrict__ Qh, bf16* __restrict__ Kh, bf16* __restrict__ Vt,
    int M, int N, int K) {
  // 36.9KB shared: sized for the epilogue scratch (4 waves x 64x72 bf16 =
  // 36864B); the K-loop staging (2 x 128 x 40 bf16 = 20480B) uses the front.
  __shared__ __align__(16) bf16 smem[4 * 64 * 72];
  bf16* As = smem;              // As[r][c] = smem[r*40+c]
  bf16* Bs = smem + 128 * 40;
  const int tid = threadIdx.x;
  const int m0 = blockIdx.y * 128, n0 = blockIdx.x * 128;
  const int wave = tid >> 6, lane = tid & 63;
  const int l15 = lane & 15, quad = lane >> 4;
  const int wm = (wave >> 1) * 64, wn = (wave & 1) * 64;

  const floatx4 fzero = {0.f, 0.f, 0.f, 0.f};
  floatx4 acc[4][4];
#pragma unroll
  for (int mi = 0; mi < 4; mi++)
#pragma unroll
    for (int ni = 0; ni < 4; ni++) acc[mi][ni] = fzero;

  const int row0 = tid >> 2;            // 0..63
  const int colb = (tid & 3) << 3;      // 0,8,16,24

  for (int k0 = 0; k0 < K; k0 += 32) {
    __syncthreads();
    *(float4*)(As + row0 * 40 + colb) =
        *(const float4*)(A + (size_t)(m0 + row0) * K + k0 + colb);
    *(float4*)(As + (row0 + 64) * 40 + colb) =
        *(const float4*)(A + (size_t)(m0 + row0 + 64) * K + k0 + colb);
    *(float4*)(Bs + row0 * 40 + colb) =
        *(const float4*)(Bt + (size_t)(n0 + row0) * K + k0 + colb);
    *(float4*)(Bs + (row0 + 64) * 40 + colb) =
        *(const float4*)(Bt + (size_t)(n0 + row0 + 64) * K + k0 + colb);
    __syncthreads();

    bf16x8 a[4], b[4];
#pragma unroll
    for (int mi = 0; mi < 4; mi++)
      a[mi] = *(const bf16x8*)(As + (wm + mi * 16 + l15) * 40 + quad * 8);
#pragma unroll
    for (int ni = 0; ni < 4; ni++)
      b[ni] = *(const bf16x8*)(Bs + (wn + ni * 16 + l15) * 40 + quad * 8);
#pragma unroll
    for (int mi = 0; mi < 4; mi++)
#pragma unroll
      for (int ni = 0; ni < 4; ni++)
        acc[mi][ni] = __builtin_amdgcn_mfma_f32_16x16x32_bf16(
            a[mi], b[ni], acc[mi][ni], 0, 0, 0);
  }

  // ---- Epilogue. C/D layout: col = lane&15, row = quad*4 + reg. ----
  __syncthreads();  // all waves done with As/Bs; reuse as scratch

  if (MODE == 1) {
    bf16* ep = smem + (size_t)wave * (64 * 72);  // 4 x 9216B = 36864B
    const int cbase = n0 + wn;                   // multiple of 64
    const int sec = cbase >> 10;                 // 0=q 1=k 2=v (wave-uniform)
    const int hh = (cbase & 1023) >> 6;          // head (uniform per wave)
    if (sec == 2) {
      // stage V^T: ep[d][t_rel], stride 72
#pragma unroll
      for (int ni = 0; ni < 4; ni++) {
        const int d = ni * 16 + l15;
        const float bv = bias[cbase + d];
#pragma unroll
        for (int mi = 0; mi < 4; mi++)
#pragma unroll
          for (int r = 0; r < 4; r++)
            ep[(size_t)d * 72 + mi * 16 + quad * 4 + r] =
                __float2bfloat16(acc[mi][ni][r] + bv);
      }
      __asm__ __volatile__("" ::: "memory");  // same-wave DS order
#pragma unroll
      for (int it = 0; it < 8; it++) {
        const int dr = it * 8 + (lane >> 3);
        const int t8 = (lane & 7) * 8;
        const bf16x8 vv = *(const bf16x8*)(ep + (size_t)dr * 72 + t8);
        *(bf16x8*)(Vt + ((size_t)hh * HDIM + dr) * TSEQ + m0 + wm + t8) = vv;
      }
    } else {
      bf16* dst = (sec == 0) ? Qh : Kh;
      // stage RoPE'd rows: ep[t_rel][c], stride 72
#pragma unroll
      for (int ni = 0; ni < 4; ni++) {
        const int c = ni * 16 + l15;  // == d, 0..63
        const float bv = bias[cbase + c];
        const int j = c & 31;
#pragma unroll
        for (int mi = 0; mi < 4; mi++) {
#pragma unroll
          for (int r = 0; r < 4; r++) {
            const int t = m0 + wm + mi * 16 + quad * 4 + r;
            const float v = acc[mi][ni][r] + bv;
            const float partner = __shfl_xor(v, 1, 64);  // col^1 in lane^1
            const float cs = tab[t * 64 + j];
            const float sn = tab[t * 64 + 32 + j];
            const float res = v * cs + ((c & 1) ? partner : -partner) * sn;
            ep[(size_t)(mi * 16 + quad * 4 + r) * 72 + c] =
                __float2bfloat16(res);
          }
        }
      }
      __asm__ __volatile__("" ::: "memory");
#pragma unroll
      for (int it = 0; it < 8; it++) {
        const int row = it * 8 + (lane >> 3);
        const int c8 = (lane & 7) * 8;
        const bf16x8 vv = *(const bf16x8*)(ep + (size_t)row * 72 + c8);
        *(bf16x8*)(dst + ((size_t)hh * TSEQ + m0 + wm + row) * HDIM + c8) = vv;
      }
    }
  } else {
    float* ep32 = (float*)smem + (size_t)wave * (32 * 68);  // 4 x 8704B
    float bvv[4];
#pragma unroll
    for (int ni = 0; ni < 4; ni++) bvv[ni] = bias[n0 + wn + ni * 16 + l15];
#pragma unroll
    for (int half = 0; half < 2; half++) {
      if (half) __asm__ __volatile__("" ::: "memory");
#pragma unroll
      for (int ni = 0; ni < 4; ni++)
#pragma unroll
        for (int mi2 = 0; mi2 < 2; mi2++)
#pragma unroll
          for (int r = 0; r < 4; r++)
            ep32[(size_t)(mi2 * 16 + quad * 4 + r) * 68 + ni * 16 + l15] =
                acc[half * 2 + mi2][ni][r] + bvv[ni];
      __asm__ __volatile__("" ::: "memory");
#pragma unroll
      for (int it = 0; it < 8; it++) {
        const int row = it * 4 + (lane >> 4);
        const float4 vv = *(const float4*)(ep32 + (size_t)row * 68 + l15 * 4);
        *(float4*)(Cout + (size_t)(m0 + wm + half * 32 + row) * N + n0 + wn +
                   l15 * 4) = vv;
      }
    }
  }
}

// -------- flash attention, S-transposed, paired q-tiles, K prefetch --------
// grid (32, NHEAD): block p handles q-tiles (p, 63-p) of 64 rows each.
// 4 waves; wave w owns 16-row slices of both tiles (2 independent chains
// sharing one K/V fetch). K fragments are double-buffered in registers so
// the next kv-block's loads issue before this iteration's compute.
// S^T = K(A) x Q(B): col=lane&15=q, row=quad*4+r=kv -> per-lane row stats
// (2 shfls); O^T = V^T(A) x P^T(B): col=q, row=d.
__global__ __launch_bounds__(256) void attn_kernel(
    const bf16* __restrict__ Qh, const bf16* __restrict__ Kh,
    const bf16* __restrict__ Vt, bf16* __restrict__ Y) {
  const int h = blockIdx.y;
  const int p = blockIdx.x;  // pair index
  const int tile_lo = p, tile_hi = 63 - p;
  const int tid = threadIdx.x;
  const int w = tid >> 6, lane = tid & 63;
  const int l15 = lane & 15, quad = lane >> 4;
  const int q_lo = tile_lo * 64 + w * 16 + l15;
  const int q_hi = tile_hi * 64 + w * 16 + l15;
  const int nkv_lo = tile_lo + 1;  // 64-wide kv tiles for lo qtile
  const int nkv_hi = tile_hi + 1;

  const bf16* Qb = Qh + (size_t)h * TSEQ * HDIM;
  const bf16* Kb = Kh + (size_t)h * TSEQ * HDIM;
  const bf16* Vb = Vt + (size_t)h * HDIM * TSEQ;

  // per-wave P^T scratch: [q-row 0..31][kv 0..63], stride 72 bf16 (144 B)
  __shared__ bf16 Plds[4][32][72];

  // Q B-fragments: n=lane&15 (q-row), k=quad*8+j (+32*ks) over d
  bf16x8 qf[2][2];  // [qt: 0=lo 1=hi][ks]
#pragma unroll
  for (int ks = 0; ks < 2; ks++) {
    qf[0][ks] = *(const bf16x8*)(Qb + (size_t)q_lo * HDIM + ks * 32 + quad * 8);
    qf[1][ks] = *(const bf16x8*)(Qb + (size_t)q_hi * HDIM + ks * 32 + quad * 8);
  }

  const floatx4 fzero = {0.f, 0.f, 0.f, 0.f};
  floatx4 o[2][4];  // [qt][dt]: O^T, col=q(l15), row=d=dt*16+quad*4+r
  float m_i[2] = {-1e30f, -1e30f}, l_i[2] = {0.f, 0.f};
#pragma unroll
  for (int qt = 0; qt < 2; qt++)
#pragma unroll
    for (int dt = 0; dt < 4; dt++) o[qt][dt] = fzero;

  const float sc = 0.125f * 1.4426950408889634f;  // 1/sqrt(64) * log2(e)

  // softmax for one qtile's S^T column (16 kv values in s[kt][r])
  auto softmax_tile = [&](floatx4* s, int qrow, bool maskit, int kv0, int qt) {
#pragma unroll
    for (int kt = 0; kt < 4; kt++) {
#pragma unroll
      for (int r = 0; r < 4; r++) {
        const float v = s[kt][r] * sc;
        if (maskit) {
          const int kv = kv0 + kt * 16 + quad * 4 + r;
          s[kt][r] = (kv <= qrow) ? v : -1e30f;
        } else {
          s[kt][r] = v;
        }
      }
    }
    float mx = -1e30f;
#pragma unroll
    for (int kt = 0; kt < 4; kt++)
#pragma unroll
      for (int r = 0; r < 4; r++) mx = fmaxf(mx, s[kt][r]);
    mx = fmaxf(mx, __shfl_xor(mx, 16, 64));
    mx = fmaxf(mx, __shfl_xor(mx, 32, 64));
    const float mnew = fmaxf(m_i[qt], mx);
    const float alpha = exp2f(m_i[qt] - mnew);
    m_i[qt] = mnew;
    float rsum = 0.f;
#pragma unroll
    for (int kt = 0; kt < 4; kt++) {
#pragma unroll
      for (int r = 0; r < 4; r++) {
        const float pv = exp2f(s[kt][r] - mnew);
        s[kt][r] = pv;
        rsum += pv;
      }
    }
    rsum += __shfl_xor(rsum, 16, 64);
    rsum += __shfl_xor(rsum, 32, 64);
    l_i[qt] = l_i[qt] * alpha + rsum;
#pragma unroll
    for (int dt = 0; dt < 4; dt++) o[qt][dt] *= alpha;
    // pack P^T to LDS: row=qt*16+l15, col=kt*16+quad*4 (+r), 4 bf16 = b64
#pragma unroll
    for (int kt = 0; kt < 4; kt++) {
      union { bf16 hh[4]; uint64_t u; } pk;
#pragma unroll
      for (int r = 0; r < 4; r++) pk.hh[r] = __float2bfloat16(s[kt][r]);
      *(uint64_t*)(&Plds[w][qt * 16 + l15][kt * 16 + quad * 4]) = pk.u;
    }
  };

  // K A-fragment loader: m=l15 (kv), k=quad*8+j over d
  auto loadK = [&](bf16x8 (&kf)[4][2], int kv0) {
#pragma unroll
    for (int kt = 0; kt < 4; kt++)
#pragma unroll
      for (int ks = 0; ks < 2; ks++)
        kf[kt][ks] = *(const bf16x8*)(Kb +
            (size_t)(kv0 + kt * 16 + l15) * HDIM + ks * 32 + quad * 8);
  };

  // one kv-block iteration using the given (already prefetched) K frags
  auto iter = [&](bf16x8 (&kf)[4][2], int kb) {
    const int kv0 = kb * 64;
    const bool lo_on = (kb < nkv_lo);

    floatx4 sh[4], sl[4];
#pragma unroll
    for (int kt = 0; kt < 4; kt++) { sh[kt] = fzero; sl[kt] = fzero; }
#pragma unroll
    for (int kt = 0; kt < 4; kt++)
#pragma unroll
      for (int ks = 0; ks < 2; ks++)
        sh[kt] = __builtin_amdgcn_mfma_f32_16x16x32_bf16(
            kf[kt][ks], qf[1][ks], sh[kt], 0, 0, 0);
    if (lo_on) {
#pragma unroll
      for (int kt = 0; kt < 4; kt++)
#pragma unroll
        for (int ks = 0; ks < 2; ks++)
          sl[kt] = __builtin_amdgcn_mfma_f32_16x16x32_bf16(
              kf[kt][ks], qf[0][ks], sl[kt], 0, 0, 0);
    }

    // V A-fragments: m=d, k over kv; latency hidden under the softmax
    bf16x8 vf[4][2];
#pragma unroll
    for (int dt = 0; dt < 4; dt++)
#pragma unroll
      for (int ks = 0; ks < 2; ks++)
        vf[dt][ks] = *(const bf16x8*)(Vb +
            (size_t)(dt * 16 + l15) * TSEQ + kv0 + ks * 32 + quad * 8);

    softmax_tile(sh, q_hi, kb == nkv_hi - 1, kv0, 1);
    if (lo_on) softmax_tile(sl, q_lo, kb == nkv_lo - 1, kv0, 0);
    __asm__ __volatile__("" ::: "memory");  // order LDS pack before reads

    // P^T B-fragments: n=q(l15), k=kv=ks*32+quad*8..+7
    bf16x8 ph[2];
#pragma unroll
    for (int ks = 0; ks < 2; ks++)
      ph[ks] = *(const bf16x8*)(&Plds[w][16 + l15][ks * 32 + quad * 8]);
#pragma unroll
    for (int dt = 0; dt < 4; dt++)
#pragma unroll
      for (int ks = 0; ks < 2; ks++)
        o[1][dt] = __builtin_amdgcn_mfma_f32_16x16x32_bf16(
            vf[dt][ks], ph[ks], o[1][dt], 0, 0, 0);
    if (lo_on) {
      bf16x8 pl[2];
#pragma unroll
      for (int ks = 0; ks < 2; ks++)
        pl[ks] = *(const bf16x8*)(&Plds[w][l15][ks * 32 + quad * 8]);
#pragma unroll
      for (int dt = 0; dt < 4; dt++)
#pragma unroll
        for (int ks = 0; ks < 2; ks++)
          o[0][dt] = __builtin_amdgcn_mfma_f32_16x16x32_bf16(
              vf[dt][ks], pl[ks], o[0][dt], 0, 0, 0);
    }
  };

  // K register double-buffer: prefetch kb+1 before computing kb
  bf16x8 kfA[4][2], kfB[4][2];
  loadK(kfA, 0);
  int kb = 0;
  while (true) {
    if (kb + 1 < nkv_hi) loadK(kfB, (kb + 1) * 64);
    iter(kfA, kb);
    if (++kb >= nkv_hi) break;
    if (kb + 1 < nkv_hi) loadK(kfA, (kb + 1) * 64);
    iter(kfB, kb);
    if (++kb >= nkv_hi) break;
  }

  // epilogue: O^T col=q(l15), row=d=dt*16+quad*4+r; write Y[q][h*64+d]
#pragma unroll
  for (int qt = 0; qt < 2; qt++) {
    const int q = (qt == 0) ? q_lo : q_hi;
    const float inv = 1.0f / l_i[qt];
#pragma unroll
    for (int dt = 0; dt < 4; dt++) {
      union { bf16 hh[4]; uint64_t u; } pk;
#pragma unroll
      for (int r = 0; r < 4; r++)
        pk.hh[r] = __float2bfloat16(o[qt][dt][r] * inv);
      *(uint64_t*)(Y + (size_t)q * CDIM + h * HDIM + dt * 16 + quad * 4) = pk.u;
    }
  }
}

extern "C" void kernel_launch(void* const* d_in, const int* in_sizes, int n_in,
                              void* d_out, int out_size, void* d_ws,
                              size_t ws_size, hipStream_t stream) {
  const float* x     = (const float*)d_in[0];
  const float* Wqkv  = (const float*)d_in[1];
  const float* bqkv  = (const float*)d_in[2];
  const float* Wproj = (const float*)d_in[3];
  const float* bproj = (const float*)d_in[4];
  float* out = (float*)d_out;

  // 40 MiB workspace layout; Y aliases xb (xb dead after gemm1);
  // rope table aliases WprojT (WprojT transposed after gemm1).
  char* ws = (char*)d_ws;
  bf16* xb     = (bf16*)(ws);                        // 4096x1024 = 8 MiB
  bf16* Y      = (bf16*)(ws);                        // aliases xb
  bf16* WqkvT  = (bf16*)(ws + (8ull  << 20));        // 3072x1024 = 6 MiB
  bf16* WprojT = (bf16*)(ws + (14ull << 20));        // 1024x1024 = 2 MiB
  float* tab   = (float*)(ws + (14ull << 20));       // 4096x64 fp32 = 1 MiB
  bf16* Qh     = (bf16*)(ws + (16ull << 20));        // [16][4096][64] = 8 MiB
  bf16* Kh     = (bf16*)(ws + (24ull << 20));        // 8 MiB
  bf16* Vt     = (bf16*)(ws + (32ull << 20));        // [16][64][4096] = 8 MiB

  f32_to_bf16<<<dim3(4096), 256, 0, stream>>>((const float4*)x, (uint64_t*)xb,
                                              TSEQ * CDIM / 4);
  transpose_f32_bf16<<<dim3(96, 32), dim3(32, 8), 0, stream>>>(
      Wqkv, WqkvT, CDIM, 3 * CDIM);
  rope_table<<<dim3(TSEQ * 32 / 256), 256, 0, stream>>>(tab);
  gemm_bt<1><<<dim3(24, 32), 256, 0, stream>>>(
      xb, WqkvT, bqkv, tab, (float*)nullptr, Qh, Kh, Vt, TSEQ, 3 * CDIM, CDIM);
  transpose_f32_bf16<<<dim3(32, 32), dim3(32, 8), 0, stream>>>(
      Wproj, WprojT, CDIM, CDIM);  // overwrites tab (dead after gemm1)
  attn_kernel<<<dim3(32, 16), 256, 0, stream>>>(Qh, Kh, Vt, Y);
  gemm_bt<0><<<dim3(8, 32), 256, 0, stream>>>(
      Y, WprojT, bproj, (float*)nullptr, out, (bf16*)nullptr, (bf16*)nullptr,
      (bf16*)nullptr, TSEQ, CDIM, CDIM);
}

// Round 9
// 399.102 us; speedup vs baseline: 1.5475x; 1.0028x over previous
//
#include <hip/hip_runtime.h>
#include <hip/hip_bf16.h>
#include <cstdint>
#include <cstddef>

// Problem: B=1, T=4096, C=1024, NH=16, HD=64. fp32 I/O, bf16 internal compute.
// Pipeline: convert x -> bf16; transpose+convert Wqkv -> B^T bf16; rope table;
//           GEMM1(+bias+RoPE+Q-prescale, vectorized LDS-transposed stores)
//           -> transpose Wproj (overwrites rope table region)
//           -> flash attention (S-transposed, paired q-tiles, lean softmax)
//           -> GEMM2(+bias) -> fp32 out.
// Workspace footprint: 40 MiB total (Y aliases xb; rope table aliases WprojT).
constexpr int TSEQ = 4096;
constexpr int CDIM = 1024;
constexpr int NHEAD = 16;
constexpr int HDIM = 64;
// softmax scale folded into Q at gemm1: 1/sqrt(64) * log2(e)
constexpr float QSCALE = 0.125f * 1.4426950408889634f;

using bf16 = __hip_bfloat16;
typedef __bf16 bf16x8 __attribute__((ext_vector_type(8)));
typedef float floatx4 __attribute__((ext_vector_type(4)));

// packed fp32x2 -> bf16x2 (RNE) via bit trick: ~7 VALU ops for two values
__device__ inline uint32_t pk_bf16_rne(float a, float b) {
  uint32_t ua = __float_as_uint(a), ub = __float_as_uint(b);
  ua = (ua + 0x7FFFu + ((ua >> 16) & 1u)) >> 16;
  ub = (ub + 0x7FFFu + ((ub >> 16) & 1u)) & 0xFFFF0000u;
  return ua | ub;
}
__device__ inline floatx4 vmax4(floatx4 a, floatx4 b) {
  floatx4 r;
  r[0] = fmaxf(a[0], b[0]); r[1] = fmaxf(a[1], b[1]);
  r[2] = fmaxf(a[2], b[2]); r[3] = fmaxf(a[3], b[3]);
  return r;
}
__device__ inline floatx4 vadd4(floatx4 a, floatx4 b) {
  floatx4 r;
  r[0] = a[0] + b[0]; r[1] = a[1] + b[1];
  r[2] = a[2] + b[2]; r[3] = a[3] + b[3];
  return r;
}

// -------- elementwise fp32 -> bf16 (4 elems/thread) --------
__global__ __launch_bounds__(256) void f32_to_bf16(
    const float4* __restrict__ in, uint64_t* __restrict__ out, int n4) {
  const int i = blockIdx.x * 256 + threadIdx.x;
  if (i < n4) {
    const float4 v = in[i];
    union { bf16 h[4]; uint64_t u; } p;
    p.h[0] = __float2bfloat16(v.x);
    p.h[1] = __float2bfloat16(v.y);
    p.h[2] = __float2bfloat16(v.z);
    p.h[3] = __float2bfloat16(v.w);
    out[i] = p.u;
  }
}

// -------- rope table: tab[t][0..31]=cos(t*invf_j), tab[t][32..63]=sin --------
__global__ __launch_bounds__(256) void rope_table(float* __restrict__ tab) {
  const int i = blockIdx.x * 256 + threadIdx.x;  // over TSEQ*32
  const int t = i >> 5, j = i & 31;
  const float invf = exp2f((float)j * (-2.0f / 64.0f) * 13.287712379549449f);
  float sn, cs;
  sincosf((float)t * invf, &sn, &cs);
  tab[t * 64 + j] = cs;
  tab[t * 64 + 32 + j] = sn;
}

// -------- transpose + convert (fp32 -> bf16), out[c][r] = in[r][c] --------
__global__ __launch_bounds__(256) void transpose_f32_bf16(
    const float* __restrict__ in, bf16* __restrict__ out, int R, int C) {
  __shared__ float tile[32][33];
  const int c0 = blockIdx.x * 32, r0 = blockIdx.y * 32;
  const int tx = threadIdx.x, ty = threadIdx.y;  // 32 x 8
#pragma unroll
  for (int i = 0; i < 32; i += 8)
    tile[ty + i][tx] = in[(size_t)(r0 + ty + i) * C + c0 + tx];
  __syncthreads();
#pragma unroll
  for (int i = 0; i < 32; i += 8)
    out[(size_t)(c0 + ty + i) * R + r0 + tx] = __float2bfloat16(tile[tx][ty + i]);
}

// -------- GEMM: C = A(MxK,bf16) * Bt(NxK,bf16)^T + bias(fp32) --------
// MODE 0: fp32 output to Cout[M][N] (vectorized via LDS transpose scratch).
// MODE 1: qkv epilogue: cols [0,1024)=q -> RoPE * QSCALE -> Qh[h][t][64];
//         [1024,2048)=k -> RoPE -> Kh; [2048,3072)=v -> Vt[h][d][t].
template <int MODE>
__global__ __launch_bounds__(256) void gemm_bt(
    const bf16* __restrict__ A, const bf16* __restrict__ Bt,
    const float* __restrict__ bias, const float* __restrict__ tab,
    float* __restrict__ Cout,
    bf16* __restrict__ Qh, bf16* __restrict__ Kh, bf16* __restrict__ Vt,
    int M, int N, int K) {
  // 36.9KB shared: sized for the epilogue scratch (4 waves x 64x72 bf16 =
  // 36864B); the K-loop staging (2 x 128 x 40 bf16 = 20480B) uses the front.
  __shared__ __align__(16) bf16 smem[4 * 64 * 72];
  bf16* As = smem;              // As[r][c] = smem[r*40+c]
  bf16* Bs = smem + 128 * 40;
  const int tid = threadIdx.x;
  const int m0 = blockIdx.y * 128, n0 = blockIdx.x * 128;
  const int wave = tid >> 6, lane = tid & 63;
  const int l15 = lane & 15, quad = lane >> 4;
  const int wm = (wave >> 1) * 64, wn = (wave & 1) * 64;

  const floatx4 fzero = {0.f, 0.f, 0.f, 0.f};
  floatx4 acc[4][4];
#pragma unroll
  for (int mi = 0; mi < 4; mi++)
#pragma unroll
    for (int ni = 0; ni < 4; ni++) acc[mi][ni] = fzero;

  const int row0 = tid >> 2;            // 0..63
  const int colb = (tid & 3) << 3;      // 0,8,16,24

  for (int k0 = 0; k0 < K; k0 += 32) {
    __syncthreads();
    *(float4*)(As + row0 * 40 + colb) =
        *(const float4*)(A + (size_t)(m0 + row0) * K + k0 + colb);
    *(float4*)(As + (row0 + 64) * 40 + colb) =
        *(const float4*)(A + (size_t)(m0 + row0 + 64) * K + k0 + colb);
    *(float4*)(Bs + row0 * 40 + colb) =
        *(const float4*)(Bt + (size_t)(n0 + row0) * K + k0 + colb);
    *(float4*)(Bs + (row0 + 64) * 40 + colb) =
        *(const float4*)(Bt + (size_t)(n0 + row0 + 64) * K + k0 + colb);
    __syncthreads();

    bf16x8 a[4], b[4];
#pragma unroll
    for (int mi = 0; mi < 4; mi++)
      a[mi] = *(const bf16x8*)(As + (wm + mi * 16 + l15) * 40 + quad * 8);
#pragma unroll
    for (int ni = 0; ni < 4; ni++)
      b[ni] = *(const bf16x8*)(Bs + (wn + ni * 16 + l15) * 40 + quad * 8);
#pragma unroll
    for (int mi = 0; mi < 4; mi++)
#pragma unroll
      for (int ni = 0; ni < 4; ni++)
        acc[mi][ni] = __builtin_amdgcn_mfma_f32_16x16x32_bf16(
            a[mi], b[ni], acc[mi][ni], 0, 0, 0);
  }

  // ---- Epilogue. C/D layout: col = lane&15, row = quad*4 + reg. ----
  __syncthreads();  // all waves done with As/Bs; reuse as scratch

  if (MODE == 1) {
    bf16* ep = smem + (size_t)wave * (64 * 72);  // 4 x 9216B = 36864B
    const int cbase = n0 + wn;                   // multiple of 64
    const int sec = cbase >> 10;                 // 0=q 1=k 2=v (wave-uniform)
    const int hh = (cbase & 1023) >> 6;          // head (uniform per wave)
    if (sec == 2) {
      // stage V^T: ep[d][t_rel], stride 72
#pragma unroll
      for (int ni = 0; ni < 4; ni++) {
        const int d = ni * 16 + l15;
        const float bv = bias[cbase + d];
#pragma unroll
        for (int mi = 0; mi < 4; mi++)
#pragma unroll
          for (int r = 0; r < 4; r++)
            ep[(size_t)d * 72 + mi * 16 + quad * 4 + r] =
                __float2bfloat16(acc[mi][ni][r] + bv);
      }
      __asm__ __volatile__("" ::: "memory");  // same-wave DS order
#pragma unroll
      for (int it = 0; it < 8; it++) {
        const int dr = it * 8 + (lane >> 3);
        const int t8 = (lane & 7) * 8;
        const bf16x8 vv = *(const bf16x8*)(ep + (size_t)dr * 72 + t8);
        *(bf16x8*)(Vt + ((size_t)hh * HDIM + dr) * TSEQ + m0 + wm + t8) = vv;
      }
    } else {
      bf16* dst = (sec == 0) ? Qh : Kh;
      const float postscale = (sec == 0) ? QSCALE : 1.0f;
      // stage RoPE'd rows: ep[t_rel][c], stride 72
#pragma unroll
      for (int ni = 0; ni < 4; ni++) {
        const int c = ni * 16 + l15;  // == d, 0..63
        const float bv = bias[cbase + c];
        const int j = c & 31;
#pragma unroll
        for (int mi = 0; mi < 4; mi++) {
#pragma unroll
          for (int r = 0; r < 4; r++) {
            const int t = m0 + wm + mi * 16 + quad * 4 + r;
            const float v = acc[mi][ni][r] + bv;
            const float partner = __shfl_xor(v, 1, 64);  // col^1 in lane^1
            const float cs = tab[t * 64 + j];
            const float sn = tab[t * 64 + 32 + j];
            const float res =
                (v * cs + ((c & 1) ? partner : -partner) * sn) * postscale;
            ep[(size_t)(mi * 16 + quad * 4 + r) * 72 + c] =
                __float2bfloat16(res);
          }
        }
      }
      __asm__ __volatile__("" ::: "memory");
#pragma unroll
      for (int it = 0; it < 8; it++) {
        const int row = it * 8 + (lane >> 3);
        const int c8 = (lane & 7) * 8;
        const bf16x8 vv = *(const bf16x8*)(ep + (size_t)row * 72 + c8);
        *(bf16x8*)(dst + ((size_t)hh * TSEQ + m0 + wm + row) * HDIM + c8) = vv;
      }
    }
  } else {
    float* ep32 = (float*)smem + (size_t)wave * (32 * 68);  // 4 x 8704B
    float bvv[4];
#pragma unroll
    for (int ni = 0; ni < 4; ni++) bvv[ni] = bias[n0 + wn + ni * 16 + l15];
#pragma unroll
    for (int half = 0; half < 2; half++) {
      if (half) __asm__ __volatile__("" ::: "memory");
#pragma unroll
      for (int ni = 0; ni < 4; ni++)
#pragma unroll
        for (int mi2 = 0; mi2 < 2; mi2++)
#pragma unroll
          for (int r = 0; r < 4; r++)
            ep32[(size_t)(mi2 * 16 + quad * 4 + r) * 68 + ni * 16 + l15] =
                acc[half * 2 + mi2][ni][r] + bvv[ni];
      __asm__ __volatile__("" ::: "memory");
#pragma unroll
      for (int it = 0; it < 8; it++) {
        const int row = it * 4 + (lane >> 4);
        const float4 vv = *(const float4*)(ep32 + (size_t)row * 68 + l15 * 4);
        *(float4*)(Cout + (size_t)(m0 + wm + half * 32 + row) * N + n0 + wn +
                   l15 * 4) = vv;
      }
    }
  }
}

// -------- flash attention, S-transposed, paired q-tiles, lean softmax -----
// grid (32, NHEAD): block p handles q-tiles (p, 63-p) of 64 rows each.
// 4 waves; wave w owns 16-row slices of both tiles (2 independent chains
// sharing one K/V fetch). Q comes pre-scaled by QSCALE (exp2 domain).
// S^T = K(A) x Q(B): col=lane&15=q, row=quad*4+r=kv -> per-lane row stats
// (tree reduce + 2 shfls); O^T = V^T(A) x P^T(B): col=q, row=d.
__global__ __launch_bounds__(256) void attn_kernel(
    const bf16* __restrict__ Qh, const bf16* __restrict__ Kh,
    const bf16* __restrict__ Vt, bf16* __restrict__ Y) {
  const int h = blockIdx.y;
  const int p = blockIdx.x;  // pair index
  const int tile_lo = p, tile_hi = 63 - p;
  const int tid = threadIdx.x;
  const int w = tid >> 6, lane = tid & 63;
  const int l15 = lane & 15, quad = lane >> 4;
  const int q_lo = tile_lo * 64 + w * 16 + l15;
  const int q_hi = tile_hi * 64 + w * 16 + l15;
  const int nkv_lo = tile_lo + 1;  // 64-wide kv tiles for lo qtile
  const int nkv_hi = tile_hi + 1;

  const bf16* Qb = Qh + (size_t)h * TSEQ * HDIM;
  // running pointers (compile-time inner offsets)
  const bf16* kp = Kh + (size_t)h * TSEQ * HDIM + (size_t)l15 * HDIM + quad * 8;
  const bf16* vp = Vt + (size_t)h * HDIM * TSEQ + (size_t)l15 * TSEQ + quad * 8;

  // per-wave P^T scratch: [q-row 0..31][kv 0..63], stride 72 bf16 (144 B)
  __shared__ bf16 Plds[4][32][72];

  // Q B-fragments: n=lane&15 (q-row), k=quad*8+j (+32*ks) over d
  bf16x8 qf[2][2];  // [qt: 0=lo 1=hi][ks]
#pragma unroll
  for (int ks = 0; ks < 2; ks++) {
    qf[0][ks] = *(const bf16x8*)(Qb + (size_t)q_lo * HDIM + ks * 32 + quad * 8);
    qf[1][ks] = *(const bf16x8*)(Qb + (size_t)q_hi * HDIM + ks * 32 + quad * 8);
  }

  const floatx4 fzero = {0.f, 0.f, 0.f, 0.f};
  floatx4 o[2][4];  // [qt][dt]: O^T, col=q(l15), row=d=dt*16+quad*4+r
  float m_i[2] = {-1e30f, -1e30f}, l_i[2] = {0.f, 0.f};
#pragma unroll
  for (int qt = 0; qt < 2; qt++)
#pragma unroll
    for (int dt = 0; dt < 4; dt++) o[qt][dt] = fzero;

  // softmax for one qtile's S^T column (16 kv values in s[kt][r]),
  // inputs already in exp2 domain (Q pre-scaled)
  auto softmax_tile = [&](floatx4* s, int qrow, bool maskit, int kv0, int qt) {
    if (maskit) {
#pragma unroll
      for (int kt = 0; kt < 4; kt++)
#pragma unroll
        for (int r = 0; r < 4; r++) {
          const int kv = kv0 + kt * 16 + quad * 4 + r;
          if (kv > qrow) s[kt][r] = -1e30f;
        }
    }
    // tree max (depth 4) + 2 shfls
    const floatx4 m4 = vmax4(vmax4(s[0], s[1]), vmax4(s[2], s[3]));
    float mx = fmaxf(fmaxf(m4[0], m4[1]), fmaxf(m4[2], m4[3]));
    mx = fmaxf(mx, __shfl_xor(mx, 16, 64));
    mx = fmaxf(mx, __shfl_xor(mx, 32, 64));
    const float mnew = fmaxf(m_i[qt], mx);
    const float alpha = exp2f(m_i[qt] - mnew);
    m_i[qt] = mnew;
#pragma unroll
    for (int kt = 0; kt < 4; kt++)
#pragma unroll
      for (int r = 0; r < 4; r++) s[kt][r] = exp2f(s[kt][r] - mnew);
    // tree sum + 2 shfls
    const floatx4 s4 = vadd4(vadd4(s[0], s[1]), vadd4(s[2], s[3]));
    float rsum = (s4[0] + s4[1]) + (s4[2] + s4[3]);
    rsum += __shfl_xor(rsum, 16, 64);
    rsum += __shfl_xor(rsum, 32, 64);
    l_i[qt] = l_i[qt] * alpha + rsum;
#pragma unroll
    for (int dt = 0; dt < 4; dt++) o[qt][dt] *= alpha;
    // pack P^T to LDS via cheap RNE: row=qt*16+l15, col=kt*16+quad*4
#pragma unroll
    for (int kt = 0; kt < 4; kt++) {
      const uint32_t lo = pk_bf16_rne(s[kt][0], s[kt][1]);
      const uint32_t hi = pk_bf16_rne(s[kt][2], s[kt][3]);
      *(uint64_t*)(&Plds[w][qt * 16 + l15][kt * 16 + quad * 4]) =
          (uint64_t)lo | ((uint64_t)hi << 32);
    }
  };

  for (int kb = 0; kb < nkv_hi; kb++) {
    const int kv0 = kb * 64;
    const bool lo_on = (kb < nkv_lo);

    // K A-fragments: m=l15 (kv), k=quad*8+j over d
    bf16x8 kf[4][2];
#pragma unroll
    for (int kt = 0; kt < 4; kt++)
#pragma unroll
      for (int ks = 0; ks < 2; ks++)
        kf[kt][ks] = *(const bf16x8*)(kp + (size_t)(kv0 + kt * 16) * HDIM +
                                      ks * 32);

    floatx4 sh[4], sl[4];
#pragma unroll
    for (int kt = 0; kt < 4; kt++) { sh[kt] = fzero; sl[kt] = fzero; }
#pragma unroll
    for (int kt = 0; kt < 4; kt++)
#pragma unroll
      for (int ks = 0; ks < 2; ks++)
        sh[kt] = __builtin_amdgcn_mfma_f32_16x16x32_bf16(
            kf[kt][ks], qf[1][ks], sh[kt], 0, 0, 0);
    if (lo_on) {
#pragma unroll
      for (int kt = 0; kt < 4; kt++)
#pragma unroll
        for (int ks = 0; ks < 2; ks++)
          sl[kt] = __builtin_amdgcn_mfma_f32_16x16x32_bf16(
              kf[kt][ks], qf[0][ks], sl[kt], 0, 0, 0);
    }

    // V A-fragments: m=d, k over kv; latency hidden under the softmax
    bf16x8 vf[4][2];
#pragma unroll
    for (int dt = 0; dt < 4; dt++)
#pragma unroll
      for (int ks = 0; ks < 2; ks++)
        vf[dt][ks] = *(const bf16x8*)(vp + (size_t)(dt * 16) * TSEQ + kv0 +
                                      ks * 32);

    softmax_tile(sh, q_hi, kb == nkv_hi - 1, kv0, 1);
    if (lo_on) softmax_tile(sl, q_lo, kb == nkv_lo - 1, kv0, 0);
    __asm__ __volatile__("" ::: "memory");  // order LDS pack before reads

    // P^T B-fragments: n=q(l15), k=kv=ks*32+quad*8..+7
    bf16x8 ph[2];
#pragma unroll
    for (int ks = 0; ks < 2; ks++)
      ph[ks] = *(const bf16x8*)(&Plds[w][16 + l15][ks * 32 + quad * 8]);
#pragma unroll
    for (int dt = 0; dt < 4; dt++)
#pragma unroll
      for (int ks = 0; ks < 2; ks++)
        o[1][dt] = __builtin_amdgcn_mfma_f32_16x16x32_bf16(
            vf[dt][ks], ph[ks], o[1][dt], 0, 0, 0);
    if (lo_on) {
      bf16x8 pl[2];
#pragma unroll
      for (int ks = 0; ks < 2; ks++)
        pl[ks] = *(const bf16x8*)(&Plds[w][l15][ks * 32 + quad * 8]);
#pragma unroll
      for (int dt = 0; dt < 4; dt++)
#pragma unroll
        for (int ks = 0; ks < 2; ks++)
          o[0][dt] = __builtin_amdgcn_mfma_f32_16x16x32_bf16(
              vf[dt][ks], pl[ks], o[0][dt], 0, 0, 0);
    }
  }

  // epilogue: O^T col=q(l15), row=d=dt*16+quad*4+r; write Y[q][h*64+d]
#pragma unroll
  for (int qt = 0; qt < 2; qt++) {
    const int q = (qt == 0) ? q_lo : q_hi;
    const float inv = 1.0f / l_i[qt];
#pragma unroll
    for (int dt = 0; dt < 4; dt++) {
      const uint32_t lo = pk_bf16_rne(o[qt][dt][0] * inv, o[qt][dt][1] * inv);
      const uint32_t hi = pk_bf16_rne(o[qt][dt][2] * inv, o[qt][dt][3] * inv);
      *(uint64_t*)(Y + (size_t)q * CDIM + h * HDIM + dt * 16 + quad * 4) =
          (uint64_t)lo | ((uint64_t)hi << 32);
    }
  }
}

extern "C" void kernel_launch(void* const* d_in, const int* in_sizes, int n_in,
                              void* d_out, int out_size, void* d_ws,
                              size_t ws_size, hipStream_t stream) {
  const float* x     = (const float*)d_in[0];
  const float* Wqkv  = (const float*)d_in[1];
  const float* bqkv  = (const float*)d_in[2];
  const float* Wproj = (const float*)d_in[3];
  const float* bproj = (const float*)d_in[4];
  float* out = (float*)d_out;

  // 40 MiB workspace layout; Y aliases xb (xb dead after gemm1);
  // rope table aliases WprojT (WprojT transposed after gemm1).
  char* ws = (char*)d_ws;
  bf16* xb     = (bf16*)(ws);                        // 4096x1024 = 8 MiB
  bf16* Y      = (bf16*)(ws);                        // aliases xb
  bf16* WqkvT  = (bf16*)(ws + (8ull  << 20));        // 3072x1024 = 6 MiB
  bf16* WprojT = (bf16*)(ws + (14ull << 20));        // 1024x1024 = 2 MiB
  float* tab   = (float*)(ws + (14ull << 20));       // 4096x64 fp32 = 1 MiB
  bf16* Qh     = (bf16*)(ws + (16ull << 20));        // [16][4096][64] = 8 MiB
  bf16* Kh     = (bf16*)(ws + (24ull << 20));        // 8 MiB
  bf16* Vt     = (bf16*)(ws + (32ull << 20));        // [16][64][4096] = 8 MiB

  f32_to_bf16<<<dim3(4096), 256, 0, stream>>>((const float4*)x, (uint64_t*)xb,
                                              TSEQ * CDIM / 4);
  transpose_f32_bf16<<<dim3(96, 32), dim3(32, 8), 0, stream>>>(
      Wqkv, WqkvT, CDIM, 3 * CDIM);
  rope_table<<<dim3(TSEQ * 32 / 256), 256, 0, stream>>>(tab);
  gemm_bt<1><<<dim3(24, 32), 256, 0, stream>>>(
      xb, WqkvT, bqkv, tab, (float*)nullptr, Qh, Kh, Vt, TSEQ, 3 * CDIM, CDIM);
  transpose_f32_bf16<<<dim3(32, 32), dim3(32, 8), 0, stream>>>(
      Wproj, WprojT, CDIM, CDIM);  // overwrites tab (dead after gemm1)
  attn_kernel<<<dim3(32, 16), 256, 0, stream>>>(Qh, Kh, Vt, Y);
  gemm_bt<0><<<dim3(8, 32), 256, 0, stream>>>(
      Y, WprojT, bproj, (float*)nullptr, out, (bf16*)nullptr, (bf16*)nullptr,
      (bf16*)nullptr, TSEQ, CDIM, CDIM);
}